// Round 8
// baseline (200.406 us; speedup 1.0000x reference)
//
#include <hip/hip_runtime.h>

// LDS forward collapsed to causal conv:
//   y[b,t,o] = sum_{d<=t} x[b,t-d] * K[d,o] + G[t,o]
//   K[d,o] = sum_s C[s,o] A[s]^d B[s]  (+ M[o,0,d-1] for d in 1..5)
//   G[t,o] = sum_s C[s,o] A[s]^{t+1} h0[s]
//
// R8 = MEASUREMENT ROUND: exact R6 kernels, but k_main launched TWICE
// (idempotent). k_main_time = total_R8 - total_R6; prep = total_R6 - k_main.

typedef __attribute__((ext_vector_type(8))) short short8v;
typedef __attribute__((ext_vector_type(4))) float float4v;

#define NB 32
#define SIG(e) ((e) + ((e) >> 3))   // pad: entry e -> slot e + e/8

static __device__ __forceinline__ unsigned short f2bf(float f) {
    union { float f; unsigned int u; } x; x.f = f;
    unsigned int r = x.u + 0x7fffu + ((x.u >> 16) & 1u);  // RNE
    return (unsigned short)(r >> 16);
}

// K1: PBT[s][d] = A[s]^d * B[s];  PHT[s][d] = A[s]^(d+1) * h0[s]
__global__ __launch_bounds__(512) void k_tables(const float* __restrict__ A,
                                                const float* __restrict__ B,
                                                const float* __restrict__ h0,
                                                float* __restrict__ PBT,
                                                float* __restrict__ PHT) {
    int s = blockIdx.x;
    int d = threadIdx.x;
    float a = A[s];
    float r = 1.0f, base = a;
    #pragma unroll
    for (int bit = 0; bit < 9; ++bit) {
        if (d & (1 << bit)) r *= base;
        base *= base;
    }
    PBT[s * 512 + d] = r * B[s];
    PHT[s * 512 + d] = r * a * h0[s];
}

// K1b: XS[b][SIG(e)] = octet(e) of reversed x; unused slots zeroed.
// stride 1216 slots per batch.
__global__ __launch_bounds__(256) void k_xprep(const float* __restrict__ x,
                                               short8v* __restrict__ XS) {
    __shared__ unsigned short xs[512];
    const int b = blockIdx.x, tid = threadIdx.x;
    #pragma unroll
    for (int q = 0; q < 2; ++q) {
        int i = tid * 2 + q;
        xs[i] = f2bf(x[b * 512 + 511 - i]);
    }
    __syncthreads();
    short8v* dst = XS + (size_t)b * 1216;
    for (int s = tid; s < 1216; s += 256) {
        if (s % 9 == 8 || s > 1150) dst[s] = (short8v)(short)0;
    }
    #pragma unroll
    for (int q = 0; q < 4; ++q) {
        int e = tid * 4 + q;
        short8v v;
        #pragma unroll
        for (int jj = 0; jj < 8; ++jj) {
            int i = e + jj;
            v[jj] = (i < 512) ? (short)xs[i] : (short)0;
        }
        dst[SIG(e)] = v;
    }
}

// K2: KT[o][d] (bf16, o-major) and G[t][o] (f32).
__global__ __launch_bounds__(256) void k_ktg(const float* __restrict__ C,
                                             const float* __restrict__ M,
                                             const float* __restrict__ PBT,
                                             const float* __restrict__ PHT,
                                             unsigned short* __restrict__ KT,
                                             float* __restrict__ G) {
    __shared__ float red[4][64][8];
    const int lane = threadIdx.x & 63;
    const int sc   = threadIdx.x >> 6;          // 0..3 s-chunk
    const int o    = blockIdx.y * 64 + lane;
    const int d0   = blockIdx.x * 4;

    float kt[4] = {0.f, 0.f, 0.f, 0.f};
    float gg[4] = {0.f, 0.f, 0.f, 0.f};
    #pragma unroll 4
    for (int si = 0; si < 128; ++si) {
        int s = sc * 128 + si;
        float c = C[s * 512 + o];
        const float* pb = PBT + s * 512 + d0;   // wave-uniform -> scalar loads
        const float* ph = PHT + s * 512 + d0;
        #pragma unroll
        for (int j = 0; j < 4; ++j) {
            kt[j] = fmaf(pb[j], c, kt[j]);
            gg[j] = fmaf(ph[j], c, gg[j]);
        }
    }
    #pragma unroll
    for (int j = 0; j < 4; ++j) {
        red[sc][lane][j]     = kt[j];
        red[sc][lane][j + 4] = gg[j];
    }
    __syncthreads();
    if (sc == 0) {
        #pragma unroll
        for (int j = 0; j < 4; ++j) {
            float v = red[0][lane][j] + red[1][lane][j] + red[2][lane][j] + red[3][lane][j];
            float g = red[0][lane][j+4] + red[1][lane][j+4] + red[2][lane][j+4] + red[3][lane][j+4];
            int d = d0 + j;
            if (d >= 1 && d <= 5) v += M[o * 5 + (d - 1)];   // AR taps
            KT[o * 512 + d] = f2bf(v);
            G[d * 512 + o]  = g;
        }
    }
}

// K3: grid (8 o-blocks, 4 t-blocks, 8 batch-groups) = 256 blocks, 512 thr.
__global__ __launch_bounds__(512, 2) void k_main(const short8v* __restrict__ XS,
                                                 const unsigned short* __restrict__ KT,
                                                 const float* __restrict__ G,
                                                 float* __restrict__ out) {
    __shared__ short8v kt_lds[4096];      // 64 KB, XOR-swizzled [o][k]
    __shared__ short8v xbuf[2][1216];     // 38 KB, sigma-padded octet tables

    const int bo0 = blockIdx.x * 64;
    const int bt0 = blockIdx.y * 128;
    const int b0  = blockIdx.z * NB;
    const int tid = threadIdx.x;
    const int lane = tid & 63;
    const int w    = tid >> 6;
    const int wm   = w >> 2, wn = w & 3;
    const int t0w  = bt0 + wm * 64;
    const int lrow = lane & 15;
    const int g    = lane >> 4;

    // ---- prologue: issue all loads, then write LDS, one sync ----
    const short8v* s0 = XS + (size_t)b0 * 1216;
    short8v x0 = s0[tid], x1 = s0[tid + 512], x2;
    if (tid < 192) x2 = s0[tid + 1024];

    short8v kreg[8];
    #pragma unroll
    for (int r = 0; r < 8; ++r) {
        int c = tid + r * 512;
        int ol = c >> 6, cc = c & 63;
        kreg[r] = *(const short8v*)(KT + (bo0 + ol) * 512 + cc * 8);
    }

    float4v gacc[4];
    #pragma unroll
    for (int mi = 0; mi < 4; ++mi)
        gacc[mi] = *(const float4v*)(G + (t0w + mi * 16 + lrow) * 512
                                       + bo0 + wn * 16 + g * 4);

    char* klw = (char*)kt_lds;
    #pragma unroll
    for (int r = 0; r < 8; ++r) {
        int c = tid + r * 512;
        int ol = c >> 6, cc = c & 63;
        int byte = (ol * 1024 + cc * 16) ^ ((ol & 7) << 4);
        *(short8v*)(klw + byte) = kreg[r];
    }
    xbuf[0][tid] = x0;
    xbuf[0][tid + 512] = x1;
    if (tid < 192) xbuf[0][tid + 1024] = x2;
    __syncthreads();

    const char* kl  = (const char*)kt_lds;
    const int  oby  = (wn * 16 + lrow) * 1024;   // byte base of this wave's o-row
    const int  swz  = (lrow & 7) << 4;
    const int  E0   = 511 - t0w - lrow + g * 8;  // A entry base (frag j at SIG(E0+16j))
    const int  ocol = bo0 + wn * 16 + g * 4;     // output o base (float4)

    int p = 0;
    for (int bi = 0; bi < NB; ++bi) {
        const int b = b0 + bi;

        // issue next batch's staging loads early (drain under MFMA loop)
        short8v nx0, nx1, nx2;
        if (bi + 1 < NB) {
            const short8v* s = XS + (size_t)(b + 1) * 1216;
            nx0 = s[tid];
            nx1 = s[tid + 512];
            if (tid < 192) nx2 = s[tid + 1024];
        }

        const short8v* xo = xbuf[p];

        float4v acc[4];
        #pragma unroll
        for (int mi = 0; mi < 4; ++mi) acc[mi] = (float4v)(0.0f);

        // init windows: B 2-ahead, A frags j=-3..0
        short8v bf[4], aw[8];
        bf[0] = *(const short8v*)(kl + ((oby + 0 * 64 + g * 16) ^ swz));
        bf[1] = *(const short8v*)(kl + ((oby + 1 * 64 + g * 16) ^ swz));
        #pragma unroll
        for (int j = -3; j <= 0; ++j)
            aw[j & 7] = xo[SIG(E0 + 16 * j)];

        #pragma unroll
        for (int ks = 0; ks < 16; ++ks) {
            if (ks < 14)
                bf[(ks + 2) & 3] = *(const short8v*)(kl + ((oby + (ks + 2) * 64 + g * 16) ^ swz));
            acc[3] = __builtin_amdgcn_mfma_f32_16x16x32_bf16(
                bf[ks & 3], aw[(2 * ks - 3) & 7], acc[3], 0, 0, 0);
            acc[2] = __builtin_amdgcn_mfma_f32_16x16x32_bf16(
                bf[ks & 3], aw[(2 * ks - 2) & 7], acc[2], 0, 0, 0);
            if (ks < 15) {
                aw[(2 * ks + 1) & 7] = xo[SIG(E0 + 16 * (2 * ks + 1))];
                aw[(2 * ks + 2) & 7] = xo[SIG(E0 + 16 * (2 * ks + 2))];
            }
            acc[1] = __builtin_amdgcn_mfma_f32_16x16x32_bf16(
                bf[ks & 3], aw[(2 * ks - 1) & 7], acc[1], 0, 0, 0);
            acc[0] = __builtin_amdgcn_mfma_f32_16x16x32_bf16(
                bf[ks & 3], aw[(2 * ks) & 7], acc[0], 0, 0, 0);
        }

        // epilogue: D row = o (g*4 + r contiguous), col = t (lrow)
        float* op = out + (size_t)b * 262144;
        #pragma unroll
        for (int mi = 0; mi < 4; ++mi) {
            const int t = t0w + mi * 16 + lrow;
            *(float4v*)(op + t * 512 + ocol) = acc[mi] + gacc[mi];
        }

        // write next buffer; lgkm-only barrier so global stores keep draining
        if (bi + 1 < NB) {
            short8v* xw = xbuf[p ^ 1];
            xw[tid] = nx0;
            xw[tid + 512] = nx1;
            if (tid < 192) xw[tid + 1024] = nx2;
            asm volatile("s_waitcnt lgkmcnt(0)" ::: "memory");
            __builtin_amdgcn_s_barrier();
            p ^= 1;
        }
    }
}

extern "C" void kernel_launch(void* const* d_in, const int* in_sizes, int n_in,
                              void* d_out, int out_size, void* d_ws, size_t ws_size,
                              hipStream_t stream) {
    const float* x  = (const float*)d_in[0];   // [256,512,1]
    const float* A  = (const float*)d_in[1];   // [512]
    const float* B  = (const float*)d_in[2];   // [1,512]
    const float* C  = (const float*)d_in[3];   // [512,512]
    const float* M  = (const float*)d_in[4];   // [512,1,5]
    const float* h0 = (const float*)d_in[5];   // [512]
    float* out = (float*)d_out;

    char* ws = (char*)d_ws;
    float*          PBT = (float*)ws;                              // 1 MB
    float*          PHT = (float*)(ws + (1u << 20));               // 1 MB
    unsigned short* KT  = (unsigned short*)(ws + (2u << 20));      // 512 KB
    float*          G   = (float*)(ws + (2u << 20) + (1u << 19));  // 1 MB
    short8v*        XS  = (short8v*)(ws + (3u << 20) + (1u << 19));// ~4.75 MB

    k_tables<<<512, 512, 0, stream>>>(A, B, h0, PBT, PHT);
    k_xprep<<<256, 256, 0, stream>>>(x, XS);
    k_ktg<<<dim3(128, 8), 256, 0, stream>>>(C, M, PBT, PHT, KT, G);
    // MEASUREMENT: launch k_main twice (idempotent). k_main cost = this
    // round's total minus R6's total (124.38 us).
    k_main<<<dim3(8, 4, 256 / NB), 512, 0, stream>>>(XS, KT, G, out);
    k_main<<<dim3(8, 4, 256 / NB), 512, 0, stream>>>(XS, KT, G, out);
}

// Round 9
// 85.523 us; speedup vs baseline: 2.3433x; 2.3433x over previous
//
#include <hip/hip_runtime.h>

// LDS forward collapsed to causal conv:
//   y[b,t,o] = sum_{d<=t} x[b,t-d] * K[d,o] + G[t,o]
//   K[d,o] = sum_s C[s,o] A[s]^d B[s]  (+ M[o,0,d-1] for d in 1..5)
//   G[t,o] = sum_s C[s,o] A[s]^{t+1} h0[s]
//
// R9: two launches.
//  k_prep (1280 blocks): units 0..1023 compute KT/G self-contained (binpow
//    power tables in LDS, broadcast reads, 4-wave s-reduction); units
//    1024..1279 build the sigma-padded reversed-octet tables XS.
//  k_main (256 blocks, 1/CU): block = 512t x 32o (8 waves of 128t x 16o),
//    NB=16 batches. B-frags in regs (64 VGPR, loaded once). Toeplitz A-frags
//    from LDS, diagonal reuse j=2ks-mi: 38 ds_read_b128 per 128 MFMA.
//    Store-bound design: stores drain across lgkm-only batch barriers.

typedef __attribute__((ext_vector_type(8))) short short8v;
typedef __attribute__((ext_vector_type(4))) float float4v;

#define NB 16
#define SIG(e) ((e) + ((e) >> 3))   // pad: entry e -> slot e + e/8

static __device__ __forceinline__ unsigned short f2bf(float f) {
    union { float f; unsigned int u; } x; x.f = f;
    unsigned int r = x.u + 0x7fffu + ((x.u >> 16) & 1u);  // RNE
    return (unsigned short)(r >> 16);
}

// ---------------- prep: KT/G (blocks 0..1023) + XS (blocks 1024..1279) ----
__global__ __launch_bounds__(256) void k_prep(const float* __restrict__ A,
                                              const float* __restrict__ B,
                                              const float* __restrict__ h0,
                                              const float* __restrict__ C,
                                              const float* __restrict__ M,
                                              const float* __restrict__ x,
                                              unsigned short* __restrict__ KT,
                                              float* __restrict__ G,
                                              short8v* __restrict__ XS) {
    __shared__ float PBL[512][4];
    __shared__ float PHL[512][4];
    __shared__ float red[4][64][8];
    __shared__ unsigned short xs[512];
    const int tid = threadIdx.x;

    if (blockIdx.x < 1024) {
        // ---- ktg unit: 64 o x 4 d ----
        const int d0 = (blockIdx.x & 127) * 4;
        const int oc = blockIdx.x >> 7;

        // phase A: power tables for this d-chunk (exact binpow, f32)
        #pragma unroll
        for (int q = 0; q < 2; ++q) {
            int ss = tid + q * 256;
            float a = A[ss];
            float r = 1.0f, base = a;
            #pragma unroll
            for (int bit = 0; bit < 9; ++bit) {       // d0 <= 508
                if (d0 & (1 << bit)) r *= base;
                base *= base;
            }
            float bs = B[ss], hs = h0[ss];
            #pragma unroll
            for (int j = 0; j < 4; ++j) {
                PBL[ss][j] = r * bs;          // A^(d0+j) * B
                PHL[ss][j] = r * a * hs;      // A^(d0+j+1) * h0
                r *= a;
            }
        }
        __syncthreads();

        // phase B: s-reduction, 4 waves x 128 s each
        const int lane = tid & 63;
        const int sc   = tid >> 6;
        const int o    = oc * 64 + lane;
        float kt[4] = {0.f, 0.f, 0.f, 0.f};
        float gg[4] = {0.f, 0.f, 0.f, 0.f};
        #pragma unroll 4
        for (int si = 0; si < 128; ++si) {
            int s = sc * 128 + si;
            float c = C[s * 512 + o];
            #pragma unroll
            for (int j = 0; j < 4; ++j) {
                kt[j] = fmaf(PBL[s][j], c, kt[j]);    // broadcast LDS reads
                gg[j] = fmaf(PHL[s][j], c, gg[j]);
            }
        }
        #pragma unroll
        for (int j = 0; j < 4; ++j) {
            red[sc][lane][j]     = kt[j];
            red[sc][lane][j + 4] = gg[j];
        }
        __syncthreads();
        if (sc == 0) {
            #pragma unroll
            for (int j = 0; j < 4; ++j) {
                float v  = red[0][lane][j] + red[1][lane][j]
                         + red[2][lane][j] + red[3][lane][j];
                float gv = red[0][lane][j+4] + red[1][lane][j+4]
                         + red[2][lane][j+4] + red[3][lane][j+4];
                int d = d0 + j;
                if (d >= 1 && d <= 5) v += M[o * 5 + (d - 1)];   // AR taps
                KT[o * 512 + d] = f2bf(v);
                G[d * 512 + o]  = gv;
            }
        }
    } else {
        // ---- xprep unit: one batch ----
        const int b = blockIdx.x - 1024;
        #pragma unroll
        for (int q = 0; q < 2; ++q) {
            int i = tid * 2 + q;
            xs[i] = f2bf(x[b * 512 + 511 - i]);
        }
        __syncthreads();
        short8v* dst = XS + (size_t)b * 1216;
        for (int s2 = tid; s2 < 1216; s2 += 256) {
            if (s2 % 9 == 8 || s2 > 1150) dst[s2] = (short8v)(short)0;
        }
        #pragma unroll
        for (int q = 0; q < 4; ++q) {
            int e = tid * 4 + q;
            short8v v;
            #pragma unroll
            for (int jj = 0; jj < 8; ++jj) {
                int i = e + jj;
                v[jj] = (i < 512) ? (short)xs[i] : (short)0;
            }
            dst[SIG(e)] = v;
        }
    }
}

// ---------------- main: 256 blocks, 512 threads, block = 512t x 32o --------
__global__ __launch_bounds__(512, 2) void k_main(const short8v* __restrict__ XS,
                                                 const unsigned short* __restrict__ KT,
                                                 const float* __restrict__ G,
                                                 float* __restrict__ out) {
    __shared__ short8v xbuf[2][1216];     // 38 KB, sigma-padded octet tables

    const int bo0 = blockIdx.x * 32;
    const int b0  = blockIdx.y * NB;
    const int tid = threadIdx.x;
    const int lane = tid & 63;
    const int w    = tid >> 6;          // 0..7
    const int wm   = w >> 1, wn = w & 1;   // 4 wm x 2 wn
    const int t0w  = wm * 128;
    const int lrow = lane & 15;
    const int g    = lane >> 4;
    const int o0w  = bo0 + wn * 16;
    const int ocol = o0w + g * 4;

    // ---- prologue: batch-0 staging + B-regs + G-regs, one sync ----
    const short8v* s0 = XS + (size_t)b0 * 1216;
    short8v x0 = s0[tid], x1 = s0[tid + 512], x2;
    if (tid < 192) x2 = s0[tid + 1024];

    short8v bfr[16];                      // this wave's 16o x 512k B slice
    {
        const unsigned short* bp = KT + (o0w + lrow) * 512 + g * 8;
        #pragma unroll
        for (int ks = 0; ks < 16; ++ks)
            bfr[ks] = *(const short8v*)(bp + ks * 32);
    }

    float4v gacc[8];                      // batch-invariant G tile
    #pragma unroll
    for (int mi = 0; mi < 8; ++mi)
        gacc[mi] = *(const float4v*)(G + (t0w + mi * 16 + lrow) * 512 + ocol);

    xbuf[0][tid] = x0;
    xbuf[0][tid + 512] = x1;
    if (tid < 192) xbuf[0][tid + 1024] = x2;
    __syncthreads();

    const int E0 = 511 - t0w - lrow + g * 8;   // frag j at SIG(E0 + 16*j)

    int p = 0;
    for (int bi = 0; bi < NB; ++bi) {
        const int b = b0 + bi;

        // issue next batch's staging loads early (drain under MFMA loop)
        short8v nx0, nx1, nx2;
        if (bi + 1 < NB) {
            const short8v* s = XS + (size_t)(b + 1) * 1216;
            nx0 = s[tid];
            nx1 = s[tid + 512];
            if (tid < 192) nx2 = s[tid + 1024];
        }

        const short8v* xo = xbuf[p];

        float4v acc[8];
        #pragma unroll
        for (int mi = 0; mi < 8; ++mi) acc[mi] = (float4v)(0.0f);

        // A window: 8 frags j = 2ks-7 .. 2ks, 2 refills per k-step
        short8v aw[8];
        #pragma unroll
        for (int j = -7; j <= 0; ++j)
            aw[j & 7] = xo[SIG(E0 + 16 * j)];

        #pragma unroll
        for (int ks = 0; ks < 16; ++ks) {
            acc[7] = __builtin_amdgcn_mfma_f32_16x16x32_bf16(
                bfr[ks], aw[(2 * ks - 7) & 7], acc[7], 0, 0, 0);
            acc[6] = __builtin_amdgcn_mfma_f32_16x16x32_bf16(
                bfr[ks], aw[(2 * ks - 6) & 7], acc[6], 0, 0, 0);
            if (ks < 15) {
                aw[(2 * ks + 1) & 7] = xo[SIG(E0 + 16 * (2 * ks + 1))];
                aw[(2 * ks + 2) & 7] = xo[SIG(E0 + 16 * (2 * ks + 2))];
            }
            #pragma unroll
            for (int mi = 5; mi >= 0; --mi)
                acc[mi] = __builtin_amdgcn_mfma_f32_16x16x32_bf16(
                    bfr[ks], aw[(2 * ks - mi) & 7], acc[mi], 0, 0, 0);
        }

        // epilogue: D row = o (g*4 + r contiguous), col = t (lrow)
        float* op = out + (size_t)b * 262144;
        #pragma unroll
        for (int mi = 0; mi < 8; ++mi) {
            const int t = t0w + mi * 16 + lrow;
            *(float4v*)(op + t * 512 + ocol) = acc[mi] + gacc[mi];
        }

        // write next buffer; lgkm-only barrier so global stores keep draining
        if (bi + 1 < NB) {
            short8v* xw = xbuf[p ^ 1];
            xw[tid] = nx0;
            xw[tid + 512] = nx1;
            if (tid < 192) xw[tid + 1024] = nx2;
            asm volatile("s_waitcnt lgkmcnt(0)" ::: "memory");
            __builtin_amdgcn_s_barrier();
            p ^= 1;
        }
    }
}

extern "C" void kernel_launch(void* const* d_in, const int* in_sizes, int n_in,
                              void* d_out, int out_size, void* d_ws, size_t ws_size,
                              hipStream_t stream) {
    const float* x  = (const float*)d_in[0];   // [256,512,1]
    const float* A  = (const float*)d_in[1];   // [512]
    const float* B  = (const float*)d_in[2];   // [1,512]
    const float* C  = (const float*)d_in[3];   // [512,512]
    const float* M  = (const float*)d_in[4];   // [512,1,5]
    const float* h0 = (const float*)d_in[5];   // [512]
    float* out = (float*)d_out;

    char* ws = (char*)d_ws;
    unsigned short* KT = (unsigned short*)ws;                  // 512 KB
    float*          G  = (float*)(ws + (1u << 19));            // 1 MB
    short8v*        XS = (short8v*)(ws + (1u << 19) + (1u << 20)); // ~4.75 MB

    k_prep<<<1280, 256, 0, stream>>>(A, B, h0, C, M, x, KT, G, XS);
    k_main<<<dim3(16, 16), 512, 0, stream>>>(XS, KT, G, out);
}